// Round 4
// baseline (30.619 us; speedup 1.0000x reference)
//
#include <hip/hip_runtime.h>
#include <math.h>

#define HH   512
#define WW   512
#define KG   256
#define NPIX (HH * WW)
#define EPSF 1e-6f
#define LOG2E 1.4426950408889634f

// Single fused kernel, 4 pixels/thread.
// Per block: fold K=256 gaussians into 12-float polynomial form in LDS (once).
//   log2(w_k(x,y)) = ca*x^2 + cb*y^2 + cc*xy + cd*x + ce*y + cf
// Inner loop per gaussian: 3 broadcast ds_read_b128 amortized over 4 pixels
// (LDS return-path: 12 cyc/wave vs 80 VALU cyc/wave -> VALU-bound).
__global__ __launch_bounds__(256, 1) void gauss_render(
    const float* __restrict__ grid,          // (H,W,2)
    const float* __restrict__ mu,            // (K,2)
    const float* __restrict__ log_scales,    // (K,2)
    const float* __restrict__ theta,         // (K,)
    const float* __restrict__ color_logits,  // (K,3)
    const float* __restrict__ log_amp,       // (K,1)
    float* __restrict__ out)                 // (H,W,3)
{
    __shared__ float4 sp[3 * KG];   // 12 KB

    const int tid = threadIdx.x;
    {
        const int k = tid;                        // blockDim.x == KG == 256
        const float mx  = mu[2 * k + 0];
        const float my  = mu[2 * k + 1];
        const float sx  = expf(log_scales[2 * k + 0]);
        const float sy  = expf(log_scales[2 * k + 1]);
        const float isx = 1.0f / (sx * sx + EPSF);
        const float isy = 1.0f / (sy * sy + EPSF);
        const float t   = theta[k];
        const float c   = cosf(t);
        const float s   = sinf(t);

        const float A = c * c * isx + s * s * isy;
        const float B = s * s * isx + c * c * isy;
        const float C = 2.0f * c * s * (isx - isy);

        const float la  = log_amp[k];
        const float amp = (la > 20.0f) ? la : log1pf(expf(la));  // softplus
        const float lnA = logf(amp);

        const float ca = -0.5f * LOG2E * A;
        const float cb = -0.5f * LOG2E * B;
        const float cc = -0.5f * LOG2E * C;
        const float cd = LOG2E * (A * mx + 0.5f * C * my);
        const float ce = LOG2E * (B * my + 0.5f * C * mx);
        const float cf = LOG2E * (lnA - 0.5f * (A * mx * mx + B * my * my + C * mx * my));

        const float c0 = 1.0f / (1.0f + expf(-color_logits[3 * k + 0]));
        const float c1 = 1.0f / (1.0f + expf(-color_logits[3 * k + 1]));
        const float c2 = 1.0f / (1.0f + expf(-color_logits[3 * k + 2]));

        sp[3 * k + 0] = make_float4(ca, cb, cc, cd);
        sp[3 * k + 1] = make_float4(ce, cf, c0, c1);
        sp[3 * k + 2] = make_float4(c2, 0.0f, 0.0f, 0.0f);
    }
    __syncthreads();

    // 4 pixels per thread, coalesced within each quarter of the block's range.
    const int base = blockIdx.x * 1024 + tid;     // block covers 1024 pixels
    const int pix0 = base;
    const int pix1 = base + 256;
    const int pix2 = base + 512;
    const int pix3 = base + 768;

    const float2 g0 = reinterpret_cast<const float2*>(grid)[pix0];
    const float2 g1 = reinterpret_cast<const float2*>(grid)[pix1];
    const float2 g2 = reinterpret_cast<const float2*>(grid)[pix2];
    const float2 g3 = reinterpret_cast<const float2*>(grid)[pix3];

    const float X0 = g0.x, Y0 = g0.y, X20 = X0 * X0, Y20 = Y0 * Y0, XY0 = X0 * Y0;
    const float X1 = g1.x, Y1 = g1.y, X21 = X1 * X1, Y21 = Y1 * Y1, XY1 = X1 * Y1;
    const float X2_ = g2.x, Y2_ = g2.y, X22 = X2_ * X2_, Y22 = Y2_ * Y2_, XY2 = X2_ * Y2_;
    const float X3 = g3.x, Y3 = g3.y, X23 = X3 * X3, Y23 = Y3 * Y3, XY3 = X3 * Y3;

    float den0 = 0.f, R0 = 0.f, G0 = 0.f, B0 = 0.f;
    float den1 = 0.f, R1 = 0.f, G1 = 0.f, B1 = 0.f;
    float den2 = 0.f, R2 = 0.f, G2 = 0.f, B2 = 0.f;
    float den3 = 0.f, R3 = 0.f, G3 = 0.f, B3 = 0.f;

    #pragma unroll 4
    for (int k = 0; k < KG; ++k) {
        const float4 q0 = sp[3 * k + 0];   // ca cb cc cd
        const float4 q1 = sp[3 * k + 1];   // ce cf c0 c1
        const float4 q2 = sp[3 * k + 2];   // c2 - - -

        float e0 = fmaf(q1.x, Y0, q1.y);
        float e1 = fmaf(q1.x, Y1, q1.y);
        float e2 = fmaf(q1.x, Y2_, q1.y);
        float e3 = fmaf(q1.x, Y3, q1.y);
        e0 = fmaf(q0.w, X0, e0);  e1 = fmaf(q0.w, X1, e1);
        e2 = fmaf(q0.w, X2_, e2); e3 = fmaf(q0.w, X3, e3);
        e0 = fmaf(q0.z, XY0, e0); e1 = fmaf(q0.z, XY1, e1);
        e2 = fmaf(q0.z, XY2, e2); e3 = fmaf(q0.z, XY3, e3);
        e0 = fmaf(q0.y, Y20, e0); e1 = fmaf(q0.y, Y21, e1);
        e2 = fmaf(q0.y, Y22, e2); e3 = fmaf(q0.y, Y23, e3);
        e0 = fmaf(q0.x, X20, e0); e1 = fmaf(q0.x, X21, e1);
        e2 = fmaf(q0.x, X22, e2); e3 = fmaf(q0.x, X23, e3);

        const float w0 = __builtin_amdgcn_exp2f(e0);
        const float w1 = __builtin_amdgcn_exp2f(e1);
        const float w2 = __builtin_amdgcn_exp2f(e2);
        const float w3 = __builtin_amdgcn_exp2f(e3);

        den0 += w0; den1 += w1; den2 += w2; den3 += w3;
        R0 = fmaf(w0, q1.z, R0); R1 = fmaf(w1, q1.z, R1);
        R2 = fmaf(w2, q1.z, R2); R3 = fmaf(w3, q1.z, R3);
        G0 = fmaf(w0, q1.w, G0); G1 = fmaf(w1, q1.w, G1);
        G2 = fmaf(w2, q1.w, G2); G3 = fmaf(w3, q1.w, G3);
        B0 = fmaf(w0, q2.x, B0); B1 = fmaf(w1, q2.x, B1);
        B2 = fmaf(w2, q2.x, B2); B3 = fmaf(w3, q2.x, B3);
    }

    const float i0 = 1.0f / (den0 + EPSF);
    const float i1 = 1.0f / (den1 + EPSF);
    const float i2 = 1.0f / (den2 + EPSF);
    const float i3 = 1.0f / (den3 + EPSF);

    out[3 * pix0 + 0] = fminf(fmaxf(R0 * i0, 0.f), 1.f);
    out[3 * pix0 + 1] = fminf(fmaxf(G0 * i0, 0.f), 1.f);
    out[3 * pix0 + 2] = fminf(fmaxf(B0 * i0, 0.f), 1.f);
    out[3 * pix1 + 0] = fminf(fmaxf(R1 * i1, 0.f), 1.f);
    out[3 * pix1 + 1] = fminf(fmaxf(G1 * i1, 0.f), 1.f);
    out[3 * pix1 + 2] = fminf(fmaxf(B1 * i1, 0.f), 1.f);
    out[3 * pix2 + 0] = fminf(fmaxf(R2 * i2, 0.f), 1.f);
    out[3 * pix2 + 1] = fminf(fmaxf(G2 * i2, 0.f), 1.f);
    out[3 * pix2 + 2] = fminf(fmaxf(B2 * i2, 0.f), 1.f);
    out[3 * pix3 + 0] = fminf(fmaxf(R3 * i3, 0.f), 1.f);
    out[3 * pix3 + 1] = fminf(fmaxf(G3 * i3, 0.f), 1.f);
    out[3 * pix3 + 2] = fminf(fmaxf(B3 * i3, 0.f), 1.f);
}

extern "C" void kernel_launch(void* const* d_in, const int* in_sizes, int n_in,
                              void* d_out, int out_size, void* d_ws, size_t ws_size,
                              hipStream_t stream) {
    const float* grid         = (const float*)d_in[0];
    const float* mu           = (const float*)d_in[1];
    const float* log_scales   = (const float*)d_in[2];
    const float* theta        = (const float*)d_in[3];
    const float* color_logits = (const float*)d_in[4];
    const float* log_amp      = (const float*)d_in[5];
    float* out = (float*)d_out;

    const int threads = 256;
    const int blocks  = NPIX / (threads * 4);    // 256 blocks, 4 px/thread
    hipLaunchKernelGGL(gauss_render, dim3(blocks), dim3(threads), 0, stream,
                       grid, mu, log_scales, theta, color_logits, log_amp, out);
}